// Round 14
// baseline (268.883 us; speedup 1.0000x reference)
//
#include <hip/hip_runtime.h>

typedef __bf16 bf16_t;
typedef __bf16 bf16x8 __attribute__((ext_vector_type(8)));
typedef __bf16 bf16x2 __attribute__((ext_vector_type(2)));
typedef float  f32x4  __attribute__((ext_vector_type(4)));

#define MFMA16(a,b,c) __builtin_amdgcn_mfma_f32_16x16x32_bf16((a),(b),(c),0,0,0)

// ---- constants (problem is fixed-shape) ----
#define BB 8
#define NN 2048
#define CC 128
#define CIN 64
#define KNB 16            // neighbors
#define BNT (BB*NN)       // 16384 points

// XCD affinity: batch a block touches == blockIdx%8 == its XCD (R6-verified).
static __device__ __forceinline__ int remap256(int x) { return ((x & 7) << 5) | (x >> 3); }

static __device__ __forceinline__ bf16x8 cvt8(const float* src) {
  f32x4 a0 = *(const f32x4*)src;
  f32x4 a1 = *(const f32x4*)(src + 4);
  bf16x8 fr;
  fr[0] = (__bf16)a0[0]; fr[1] = (__bf16)a0[1]; fr[2] = (__bf16)a0[2]; fr[3] = (__bf16)a0[3];
  fr[4] = (__bf16)a1[0]; fr[5] = (__bf16)a1[1]; fr[6] = (__bf16)a1[2]; fr[7] = (__bf16)a1[3];
  return fr;
}

// ============================================================
// Kernel 1: in_proj + LN1 (R6-proven body; h stored bf16) + fused
// weight-conversion blocks (256..311).
// ============================================================
__global__ __launch_bounds__(256) void inproj_compw_k(
    const float* __restrict__ x, const float* __restrict__ Win, const float* __restrict__ bin,
    const float* __restrict__ g1, const float* __restrict__ b1,
    bf16_t* __restrict__ hb, bf16_t* __restrict__ hnb,
    const float* __restrict__ Wq, const float* __restrict__ Wk, const float* __restrict__ Wv,
    const float* __restrict__ Wd2, const float* __restrict__ Wa,
    const float* __restrict__ Wf1, const float* __restrict__ Wf2,
    bf16_t* __restrict__ Wqb, bf16_t* __restrict__ Wkb, bf16_t* __restrict__ Wvb,
    bf16_t* __restrict__ Wd2b, bf16_t* __restrict__ Wab,
    bf16_t* __restrict__ Wf1b, bf16_t* __restrict__ Wf2b) {
  __shared__ bf16_t As[64 * 72];
  __shared__ bf16_t Bs[128 * 72];
  __shared__ float hs[64 * 132];
  int t = threadIdx.x;
  if (blockIdx.x >= 256) {
    int bi = blockIdx.x - 256;
    int mat = bi >> 3, xi = bi & 7;
    int nel = (mat >= 5) ? 65536 : 16384;
    const float* S = mat == 0 ? Wq : mat == 1 ? Wk : mat == 2 ? Wv : mat == 3 ? Wd2
                   : mat == 4 ? Wa : mat == 5 ? Wf1 : Wf2;
    bf16_t* D = mat == 0 ? Wqb : mat == 1 ? Wkb : mat == 2 ? Wvb : mat == 3 ? Wd2b
              : mat == 4 ? Wab : mat == 5 ? Wf1b : Wf2b;
    for (int i = xi * 256 + t; i * 8 < nel; i += 2048)
      *(bf16x8*)(D + i * 8) = cvt8(S + i * 8);
    return;
  }
  int lane = t & 63, w = t >> 6, quad = lane >> 4, l15 = lane & 15;
  int mBase = remap256(blockIdx.x) * 64;
  int b = mBase >> 11, n0 = mBase & (NN - 1);
  const float* xb = x + (size_t)b * CIN * NN;
  {
    int k = t >> 2, part = t & 3;
    #pragma unroll
    for (int i = 0; i < 4; ++i) {
      f32x4 v = *(const f32x4*)(xb + (size_t)k * NN + n0 + part * 16 + i * 4);
      #pragma unroll
      for (int j2 = 0; j2 < 4; ++j2) As[(part * 16 + i * 4 + j2) * 72 + k] = (__bf16)v[j2];
    }
  }
  {
    int row = t >> 1, seg = (t & 1) * 32;
    #pragma unroll
    for (int i = 0; i < 4; ++i)
      *(bf16x8*)(&Bs[row * 72 + seg + i * 8]) = cvt8(Win + (size_t)row * CIN + seg + i * 8);
  }
  __syncthreads();
  f32x4 acc[2][4] = {};
  #pragma unroll
  for (int s = 0; s < 2; ++s) {
    bf16x8 af[4];
    #pragma unroll
    for (int mt = 0; mt < 4; ++mt)
      af[mt] = *(const bf16x8*)(&As[(mt * 16 + l15) * 72 + s * 32 + quad * 8]);
    #pragma unroll
    for (int t2 = 0; t2 < 2; ++t2) {
      bf16x8 bfr = *(const bf16x8*)(&Bs[((w * 2 + t2) * 16 + l15) * 72 + s * 32 + quad * 8]);
      #pragma unroll
      for (int mt = 0; mt < 4; ++mt) acc[t2][mt] = MFMA16(af[mt], bfr, acc[t2][mt]);
    }
  }
  #pragma unroll
  for (int t2 = 0; t2 < 2; ++t2) {
    int col = (w * 2 + t2) * 16 + l15;
    float bv = bin[col];
    #pragma unroll
    for (int mt = 0; mt < 4; ++mt)
      #pragma unroll
      for (int reg = 0; reg < 4; ++reg)
        hs[(mt * 16 + quad * 4 + reg) * 132 + col] = acc[t2][mt][reg] + bv;
  }
  __syncthreads();
  {
    int row = t >> 2, c0 = (t & 3) * 32;
    float v[32];
    #pragma unroll
    for (int i = 0; i < 8; ++i) *(f32x4*)(v + i * 4) = *(const f32x4*)(&hs[row * 132 + c0 + i * 4]);
    float s1 = 0.f, s2 = 0.f;
    #pragma unroll
    for (int i = 0; i < 32; ++i) { s1 += v[i]; s2 += v[i] * v[i]; }
    s1 += __shfl_xor(s1, 1); s1 += __shfl_xor(s1, 2);
    s2 += __shfl_xor(s2, 1); s2 += __shfl_xor(s2, 2);
    float mu = s1 * (1.f / CC);
    float var = s2 * (1.f / CC) - mu * mu;
    float rs = rsqrtf(var + 1e-5f);
    bf16_t* hrow = hb + (size_t)(mBase + row) * CC + c0;
    #pragma unroll
    for (int i = 0; i < 4; ++i) {
      bf16x8 ho;
      #pragma unroll
      for (int j = 0; j < 8; ++j) ho[j] = (__bf16)v[i * 8 + j];
      *(bf16x8*)(hrow + i * 8) = ho;
    }
    bf16_t* hnrow = hnb + (size_t)(mBase + row) * CC + c0;
    #pragma unroll
    for (int i = 0; i < 4; ++i) {
      f32x4 g4a = ((const f32x4*)g1)[(c0 >> 2) + i * 2],     g4b = ((const f32x4*)g1)[(c0 >> 2) + i * 2 + 1];
      f32x4 b4a = ((const f32x4*)b1)[(c0 >> 2) + i * 2],     b4b = ((const f32x4*)b1)[(c0 >> 2) + i * 2 + 1];
      bf16x8 o;
      #pragma unroll
      for (int j = 0; j < 4; ++j) o[j]     = (__bf16)((v[i * 8 + j]     - mu) * rs * g4a[j] + b4a[j]);
      #pragma unroll
      for (int j = 0; j < 4; ++j) o[4 + j] = (__bf16)((v[i * 8 + 4 + j] - mu) * rs * g4b[j] + b4b[j]);
      *(bf16x8*)(hnrow + i * 8) = o;
    }
  }
}

// ============================================================
// KNN body (R6 verbatim, LDS passed in).
// ============================================================
static __device__ __forceinline__ void cas(double& a, double& b) {
  double lo = fmin(a, b), hi = fmax(a, b); a = lo; b = hi;
}
#define S8(K,o) \
  cas(K[o+0],K[o+1]); cas(K[o+2],K[o+3]); cas(K[o+4],K[o+5]); cas(K[o+6],K[o+7]); \
  cas(K[o+0],K[o+2]); cas(K[o+1],K[o+3]); cas(K[o+4],K[o+6]); cas(K[o+5],K[o+7]); \
  cas(K[o+1],K[o+2]); cas(K[o+5],K[o+6]); \
  cas(K[o+0],K[o+4]); cas(K[o+1],K[o+5]); cas(K[o+2],K[o+6]); cas(K[o+3],K[o+7]); \
  cas(K[o+2],K[o+4]); cas(K[o+3],K[o+5]); \
  cas(K[o+1],K[o+2]); cas(K[o+3],K[o+4]); cas(K[o+5],K[o+6]);
#define M8(K,a,b) \
  K[a+0]=fmin(K[a+0],K[b+7]); K[a+1]=fmin(K[a+1],K[b+6]); K[a+2]=fmin(K[a+2],K[b+5]); K[a+3]=fmin(K[a+3],K[b+4]); \
  K[a+4]=fmin(K[a+4],K[b+3]); K[a+5]=fmin(K[a+5],K[b+2]); K[a+6]=fmin(K[a+6],K[b+1]); K[a+7]=fmin(K[a+7],K[b+0]); \
  cas(K[a+0],K[a+4]); cas(K[a+1],K[a+5]); cas(K[a+2],K[a+6]); cas(K[a+3],K[a+7]); \
  cas(K[a+0],K[a+2]); cas(K[a+1],K[a+3]); cas(K[a+4],K[a+6]); cas(K[a+5],K[a+7]); \
  cas(K[a+0],K[a+1]); cas(K[a+2],K[a+3]); cas(K[a+4],K[a+5]); cas(K[a+6],K[a+7]);

static __device__ void knn_impl(float* sp, const float* __restrict__ p,
                                int* __restrict__ idxo, int bid) {
  float* px = sp; float* py = sp + NN; float* pz = sp + 2 * NN;
  int t = threadIdx.x;
  int b = bid >> 9;
  int g = bid & 511;
  const float* pb = p + (size_t)b * 3 * NN;
  for (int i = t; i < NN; i += 256) { px[i] = pb[i]; py[i] = pb[NN + i]; pz[i] = pb[2 * NN + i]; }
  __syncthreads();
  int w = t >> 6, lane = t & 63;
  int n = g * 4 + w;
  float pnx = px[n], pny = py[n], pnz = pz[n];
  double key[32];
  #pragma unroll
  for (int s = 0; s < 32; ++s) {
    int m = s * 64 + lane;
    float dx = pnx - px[m], dy = pny - py[m], dz = pnz - pz[m];
    float dist = dx * dx + dy * dy + dz * dz;
    unsigned db = (m == n) ? 0x7F800000u : __float_as_uint(dist);
    key[s] = __hiloint2double((int)db, m);
  }
  S8(key, 0); S8(key, 8); S8(key, 16); S8(key, 24);
  M8(key, 0, 8); M8(key, 16, 24); M8(key, 0, 16);
  const double DINF = __hiloint2double(0x7F900000, 0);
  int* myout = idxo + ((size_t)b * NN + n) * KNB;
  #pragma unroll 1
  for (int r = 0; r < 16; ++r) {
    double gm = key[0];
    #pragma unroll
    for (int off = 1; off < 64; off <<= 1) {
      double o = __shfl_xor(gm, off);
      gm = fmin(gm, o);
    }
    if (lane == 0) myout[r] = __double2loint(gm);
    bool win = (key[0] == gm);
    key[0] = win ? key[1] : key[0];
    key[1] = win ? key[2] : key[1];
    key[2] = win ? key[3] : key[2];
    key[3] = win ? key[4] : key[3];
    key[4] = win ? key[5] : key[4];
    key[5] = win ? key[6] : key[5];
    key[6] = win ? key[7] : key[6];
    key[7] = win ? DINF   : key[7];
  }
}

// ============================================================
// Fused knn + qkv-3-in-1 dispatch.
// Blocks [0,4096): knn (24.6 KB LDS).
// Blocks [4096,4608): qkv — ONE block computes q,k,v for its (m,n) tile:
// A staged once (was 3x across blocks), 3 B tiles, 48 MFMA per k-chunk.
// Per-output accumulation order identical to R13 -> bit-identical results.
// LDS for qkv: 4 x 5120 B = 20.5 KB (under the knn union).
// ============================================================
__global__ __launch_bounds__(256) void knn_qkv_k(
    const float* __restrict__ p, int* __restrict__ idxo,
    const bf16_t* __restrict__ hnb,
    const bf16_t* __restrict__ Wqb, const bf16_t* __restrict__ Wkb, const bf16_t* __restrict__ Wvb,
    bf16_t* __restrict__ qb, bf16_t* __restrict__ kb, bf16_t* __restrict__ vb) {
  __shared__ __align__(16) char smem[3 * NN * 4];   // 24576 B
  if (blockIdx.x < 4096) {
    knn_impl((float*)smem, p, idxo, blockIdx.x);
    return;
  }
  bf16_t* As = (bf16_t*)smem;
  bf16_t* Bs0 = As + 2560;
  bf16_t* Bs1 = Bs0 + 2560;
  bf16_t* Bs2 = Bs1 + 2560;
  int t = threadIdx.x;
  int lane = t & 63, w = t >> 6, quad = lane >> 4, l15 = lane & 15;
  int bx = blockIdx.x - 4096;
  int xx = bx & 255, yy = bx >> 8;          // yy in {0,1}: n-half
  int mB = remap256(xx) * 64, nB = yy * 64;
  int r = t >> 2, seg = (t & 3) * 8;
  f32x4 acc[3][4] = {};
  for (int k0 = 0; k0 < CC; k0 += 32) {
    __syncthreads();
    *(bf16x8*)(&As[r * 40 + seg])  = *(const bf16x8*)(hnb + (size_t)(mB + r) * CC + k0 + seg);
    *(bf16x8*)(&Bs0[r * 40 + seg]) = *(const bf16x8*)(Wqb + (size_t)(nB + r) * CC + k0 + seg);
    *(bf16x8*)(&Bs1[r * 40 + seg]) = *(const bf16x8*)(Wkb + (size_t)(nB + r) * CC + k0 + seg);
    *(bf16x8*)(&Bs2[r * 40 + seg]) = *(const bf16x8*)(Wvb + (size_t)(nB + r) * CC + k0 + seg);
    __syncthreads();
    bf16x8 af[4];
    #pragma unroll
    for (int mt = 0; mt < 4; ++mt)
      af[mt] = *(const bf16x8*)(&As[(mt * 16 + l15) * 40 + quad * 8]);
    bf16x8 b0 = *(const bf16x8*)(&Bs0[(w * 16 + l15) * 40 + quad * 8]);
    bf16x8 b1 = *(const bf16x8*)(&Bs1[(w * 16 + l15) * 40 + quad * 8]);
    bf16x8 b2 = *(const bf16x8*)(&Bs2[(w * 16 + l15) * 40 + quad * 8]);
    #pragma unroll
    for (int mt = 0; mt < 4; ++mt) {
      acc[0][mt] = MFMA16(af[mt], b0, acc[0][mt]);
      acc[1][mt] = MFMA16(af[mt], b1, acc[1][mt]);
      acc[2][mt] = MFMA16(af[mt], b2, acc[2][mt]);
    }
  }
  int n = nB + w * 16 + l15;
  #pragma unroll
  for (int mat = 0; mat < 3; ++mat) {
    bf16_t* dst = mat == 0 ? qb : mat == 1 ? kb : vb;
    #pragma unroll
    for (int mt = 0; mt < 4; ++mt)
      #pragma unroll
      for (int reg = 0; reg < 4; ++reg) {
        int m = mB + mt * 16 + quad * 4 + reg;
        dst[(size_t)m * CC + n] = (__bf16)acc[mat][mt][reg];
      }
  }
}

// ============================================================
// FFN1: block computes 64x256 of g = relu(h2 @ Wf1^T + bf1).
// A staged once per k-chunk for 4 B tiles -> 64 MFMA/chunk.
// grid (256, 2). LDS 25.6 KB.
// ============================================================
__global__ __launch_bounds__(256) void ffn1_k(
    const bf16_t* __restrict__ h2, const bf16_t* __restrict__ Wf1b,
    const float* __restrict__ bf1, bf16_t* __restrict__ g) {
  __shared__ bf16_t As[64 * 40];
  __shared__ bf16_t Bs[4][64 * 40];
  int t = threadIdx.x;
  int lane = t & 63, w = t >> 6, quad = lane >> 4, l15 = lane & 15;
  int mB = remap256(blockIdx.x) * 64;
  int nG = blockIdx.y * 256;
  int r = t >> 2, seg = (t & 3) * 8;
  f32x4 acc[4][4] = {};
  for (int k0 = 0; k0 < CC; k0 += 32) {
    __syncthreads();
    *(bf16x8*)(&As[r * 40 + seg]) = *(const bf16x8*)(h2 + (size_t)(mB + r) * CC + k0 + seg);
    #pragma unroll
    for (int gi = 0; gi < 4; ++gi)
      *(bf16x8*)(&Bs[gi][r * 40 + seg]) =
          *(const bf16x8*)(Wf1b + (size_t)(nG + gi * 64 + r) * CC + k0 + seg);
    __syncthreads();
    bf16x8 af[4];
    #pragma unroll
    for (int mt = 0; mt < 4; ++mt)
      af[mt] = *(const bf16x8*)(&As[(mt * 16 + l15) * 40 + quad * 8]);
    #pragma unroll
    for (int gi = 0; gi < 4; ++gi) {
      bf16x8 bfr = *(const bf16x8*)(&Bs[gi][(w * 16 + l15) * 40 + quad * 8]);
      #pragma unroll
      for (int mt = 0; mt < 4; ++mt)
        acc[gi][mt] = MFMA16(af[mt], bfr, acc[gi][mt]);
    }
  }
  #pragma unroll
  for (int gi = 0; gi < 4; ++gi) {
    int n = nG + gi * 64 + w * 16 + l15;
    float bv = bf1[n];
    #pragma unroll
    for (int mt = 0; mt < 4; ++mt)
      #pragma unroll
      for (int reg = 0; reg < 4; ++reg) {
        int m = mB + mt * 16 + quad * 4 + reg;
        g[(size_t)m * (4 * CC) + n] = (__bf16)fmaxf(acc[gi][mt][reg] + bv, 0.f);
      }
  }
}

// ============================================================
// FFN2: block computes 64x128 (full N) of out = g @ Wf2^T + bf2 + resid,
// transposed store to [B,C,N]. K=512: 16 chunks x 32 MFMA. grid (256).
// ============================================================
__global__ __launch_bounds__(256) void ffn2_k(
    const bf16_t* __restrict__ g, const bf16_t* __restrict__ Wf2b,
    const float* __restrict__ bf2, const bf16_t* __restrict__ resid,
    float* __restrict__ out) {
  __shared__ bf16_t As[64 * 40];
  __shared__ bf16_t Bs[2][64 * 40];
  int t = threadIdx.x;
  int lane = t & 63, w = t >> 6, quad = lane >> 4, l15 = lane & 15;
  int mB = remap256(blockIdx.x) * 64;
  int r = t >> 2, seg = (t & 3) * 8;
  f32x4 acc[2][4] = {};
  for (int k0 = 0; k0 < 4 * CC; k0 += 32) {
    __syncthreads();
    *(bf16x8*)(&As[r * 40 + seg]) = *(const bf16x8*)(g + (size_t)(mB + r) * (4 * CC) + k0 + seg);
    #pragma unroll
    for (int hh = 0; hh < 2; ++hh)
      *(bf16x8*)(&Bs[hh][r * 40 + seg]) =
          *(const bf16x8*)(Wf2b + (size_t)(hh * 64 + r) * (4 * CC) + k0 + seg);
    __syncthreads();
    bf16x8 af[4];
    #pragma unroll
    for (int mt = 0; mt < 4; ++mt)
      af[mt] = *(const bf16x8*)(&As[(mt * 16 + l15) * 40 + quad * 8]);
    #pragma unroll
    for (int hh = 0; hh < 2; ++hh) {
      bf16x8 bfr = *(const bf16x8*)(&Bs[hh][(w * 16 + l15) * 40 + quad * 8]);
      #pragma unroll
      for (int mt = 0; mt < 4; ++mt)
        acc[hh][mt] = MFMA16(af[mt], bfr, acc[hh][mt]);
    }
  }
  #pragma unroll
  for (int hh = 0; hh < 2; ++hh) {
    int n = hh * 64 + w * 16 + l15;
    float bv = bf2[n];
    #pragma unroll
    for (int mt = 0; mt < 4; ++mt)
      #pragma unroll
      for (int reg = 0; reg < 4; ++reg) {
        int m = mB + mt * 16 + quad * 4 + reg;
        float val = acc[hh][mt][reg] + bv + (float)resid[(size_t)m * CC + n];
        int bo = m >> 11, np = m & (NN - 1);
        out[((size_t)bo * CC + n) * NN + np] = val;
      }
  }
}

// ============================================================
// Kernel 5: fused neighbor attention (R13 verbatim — 75 µs, absmax-proven).
// ============================================================
__global__ __launch_bounds__(256, 3) void attn_k(
    const bf16_t* __restrict__ qbuf, const bf16_t* __restrict__ kbuf, const bf16_t* __restrict__ vbuf,
    const float* __restrict__ p, const int* __restrict__ idx,
    const float* __restrict__ Wd1, const float* __restrict__ bd1,
    const bf16_t* __restrict__ Wd2b, const float* __restrict__ bd2,
    const bf16_t* __restrict__ Wab, const float* __restrict__ ba,
    const float* __restrict__ g2, const float* __restrict__ b2,
    const bf16_t* __restrict__ hb, bf16_t* __restrict__ hresb, bf16_t* __restrict__ h2) {
  __shared__ bf16_t ts[64 * 136];      // u matrix only
  __shared__ float hrs[4 * 128];
  __shared__ f32x4 wd1s[128];          // {Wd1[c][0..2], bd1[c]}
  __shared__ f32x4 rels4[64];          // {rx,ry,rz,0}
  __shared__ int idxs[64];
  int t = threadIdx.x;
  int lane = t & 63, w = t >> 6, quad = lane >> 4, l15 = lane & 15;
  int batch = blockIdx.x & 7, grp = blockIdx.x >> 3;
  int bn0 = batch * NN + grp * 4;
  int b = batch;
  const float* pb = p + (size_t)b * 3 * NN;
  int col0 = w * 32 + l15;
  int col1 = col0 + 16;

  bf16x8 Bd[2][4];
  #pragma unroll
  for (int t2 = 0; t2 < 2; ++t2) {
    int row = w * 32 + t2 * 16 + l15;
    #pragma unroll
    for (int s = 0; s < 4; ++s)
      Bd[t2][s] = *(const bf16x8*)(Wd2b + (size_t)row * CC + s * 32 + quad * 8);
  }

  if (t < 64) {
    int jj = idx[(size_t)bn0 * KNB + t];
    idxs[t] = jj;
    int npt = grp * 4 + (t >> 4);
    f32x4 rv;
    rv[0] = pb[npt]          - pb[jj];
    rv[1] = pb[NN + npt]     - pb[NN + jj];
    rv[2] = pb[2 * NN + npt] - pb[2 * NN + jj];
    rv[3] = 0.f;
    rels4[t] = rv;
  }
  if (t < 128) {
    f32x4 wv;
    wv[0] = Wd1[t * 3]; wv[1] = Wd1[t * 3 + 1]; wv[2] = Wd1[t * 3 + 2]; wv[3] = bd1[t];
    wd1s[t] = wv;
  }
  __syncthreads();

  float qv[2][4];
  #pragma unroll
  for (int mt = 0; mt < 4; ++mt) {
    qv[0][mt] = (float)qbuf[(size_t)(bn0 + mt) * CC + col0];
    qv[1][mt] = (float)qbuf[(size_t)(bn0 + mt) * CC + col1];
  }
  float kreg[2][4][4];
  #pragma unroll
  for (int mt = 0; mt < 4; ++mt)
    #pragma unroll
    for (int reg = 0; reg < 4; ++reg) {
      size_t base = (size_t)(b * NN + idxs[mt * 16 + quad * 4 + reg]) * CC;
      kreg[0][mt][reg] = (float)kbuf[base + col0];
      kreg[1][mt][reg] = (float)kbuf[base + col1];
    }

  f32x4 relv[4];
  #pragma unroll
  for (int mt = 0; mt < 4; ++mt) relv[mt] = rels4[mt * 16 + l15];
  f32x4 accd[2][4] = {};
  #pragma unroll
  for (int s = 0; s < 4; ++s) {
    bf16x8 af[4];
    #pragma unroll
    for (int j = 0; j < 8; ++j) {
      f32x4 wv = wd1s[s * 32 + quad * 8 + j];
      #pragma unroll
      for (int mt = 0; mt < 4; ++mt) {
        float tv = fmaf(wv[0], relv[mt][0], fmaf(wv[1], relv[mt][1], fmaf(wv[2], relv[mt][2], wv[3])));
        af[mt][j] = (__bf16)fmaxf(tv, 0.f);
      }
    }
    #pragma unroll
    for (int t2 = 0; t2 < 2; ++t2)
      #pragma unroll
      for (int mt = 0; mt < 4; ++mt)
        accd[t2][mt] = MFMA16(af[mt], Bd[t2][s], accd[t2][mt]);
  }

  {
    float b2v0 = bd2[col0], b2v1 = bd2[col1];
    #pragma unroll
    for (int mt = 0; mt < 4; ++mt)
      #pragma unroll
      for (int reg = 0; reg < 4; ++reg) {
        int row = mt * 16 + quad * 4 + reg;
        float d0 = accd[0][mt][reg] + b2v0;
        float d1 = accd[1][mt][reg] + b2v1;
        accd[0][mt][reg] = d0;
        accd[1][mt][reg] = d1;
        ts[row * 136 + col0] = (__bf16)(qv[0][mt] - kreg[0][mt][reg] + d0);
        ts[row * 136 + col1] = (__bf16)(qv[1][mt] - kreg[1][mt][reg] + d1);
      }
  }
  __syncthreads();

  float vreg[2][4][4];
  #pragma unroll
  for (int mt = 0; mt < 4; ++mt)
    #pragma unroll
    for (int reg = 0; reg < 4; ++reg) {
      size_t base = (size_t)(b * NN + idxs[mt * 16 + quad * 4 + reg]) * CC;
      vreg[0][mt][reg] = (float)vbuf[base + col0];
      vreg[1][mt][reg] = (float)vbuf[base + col1];
    }
  float hv[2][4];
  if (quad == 0) {
    #pragma unroll
    for (int mt = 0; mt < 4; ++mt) {
      hv[0][mt] = (float)hb[(size_t)(bn0 + mt) * CC + col0];
      hv[1][mt] = (float)hb[(size_t)(bn0 + mt) * CC + col1];
    }
  }
  bf16x8 Ba[2][4];
  #pragma unroll
  for (int t2 = 0; t2 < 2; ++t2) {
    int row = w * 32 + t2 * 16 + l15;
    #pragma unroll
    for (int s = 0; s < 4; ++s)
      Ba[t2][s] = *(const bf16x8*)(Wab + (size_t)row * CC + s * 32 + quad * 8);
  }

  f32x4 accl[2][4] = {};
  #pragma unroll
  for (int s = 0; s < 4; ++s) {
    bf16x8 af[4];
    #pragma unroll
    for (int mt = 0; mt < 4; ++mt)
      af[mt] = *(const bf16x8*)(&ts[(mt * 16 + l15) * 136 + s * 32 + quad * 8]);
    #pragma unroll
    for (int t2 = 0; t2 < 2; ++t2)
      #pragma unroll
      for (int mt = 0; mt < 4; ++mt)
        accl[t2][mt] = MFMA16(af[mt], Ba[t2][s], accl[t2][mt]);
  }

  #pragma unroll
  for (int t2 = 0; t2 < 2; ++t2) {
    int col = t2 ? col1 : col0;
    float bav = ba[col];
    #pragma unroll
    for (int mt = 0; mt < 4; ++mt) {
      float lv0 = accl[t2][mt][0] + bav, lv1 = accl[t2][mt][1] + bav;
      float lv2 = accl[t2][mt][2] + bav, lv3 = accl[t2][mt][3] + bav;
      float mx = fmaxf(fmaxf(lv0, lv1), fmaxf(lv2, lv3));
      mx = fmaxf(mx, __shfl_xor(mx, 16));
      mx = fmaxf(mx, __shfl_xor(mx, 32));
      float e0 = __expf(lv0 - mx), e1 = __expf(lv1 - mx);
      float e2 = __expf(lv2 - mx), e3 = __expf(lv3 - mx);
      float ss = e0 + e1 + e2 + e3;
      ss += __shfl_xor(ss, 16); ss += __shfl_xor(ss, 32);
      float yv = e0 * (vreg[t2][mt][0] + accd[t2][mt][0])
               + e1 * (vreg[t2][mt][1] + accd[t2][mt][1])
               + e2 * (vreg[t2][mt][2] + accd[t2][mt][2])
               + e3 * (vreg[t2][mt][3] + accd[t2][mt][3]);
      yv += __shfl_xor(yv, 16); yv += __shfl_xor(yv, 32);
      if (quad == 0) {
        float hvv = hv[t2][mt] + yv / ss;
        hresb[(size_t)(bn0 + mt) * CC + col] = (__bf16)hvv;
        hrs[mt * 128 + col] = hvv;
      }
    }
  }
  __syncthreads();

  {
    int c0 = lane * 2;
    float v0 = hrs[w * 128 + c0], v1 = hrs[w * 128 + c0 + 1];
    float s1 = v0 + v1, s2 = v0 * v0 + v1 * v1;
    #pragma unroll
    for (int off = 1; off < 64; off <<= 1) { s1 += __shfl_xor(s1, off); s2 += __shfl_xor(s2, off); }
    float mu = s1 * (1.f / CC);
    float var = s2 * (1.f / CC) - mu * mu;
    float rs = rsqrtf(var + 1e-5f);
    bf16x2 o;
    o[0] = (__bf16)((v0 - mu) * rs * g2[c0] + b2[c0]);
    o[1] = (__bf16)((v1 - mu) * rs * g2[c0 + 1] + b2[c0 + 1]);
    *(bf16x2*)(h2 + (size_t)(bn0 + w) * CC + c0) = o;
  }
}

// ============================================================
extern "C" void kernel_launch(void* const* d_in, const int* in_sizes, int n_in,
                              void* d_out, int out_size, void* d_ws, size_t ws_size,
                              hipStream_t stream) {
  const float* x   = (const float*)d_in[0];
  const float* p   = (const float*)d_in[1];
  const float* Win = (const float*)d_in[2];
  const float* bin = (const float*)d_in[3];
  const float* Wq  = (const float*)d_in[4];
  const float* Wk  = (const float*)d_in[5];
  const float* Wv  = (const float*)d_in[6];
  const float* Wd1 = (const float*)d_in[7];
  const float* bd1 = (const float*)d_in[8];
  const float* Wd2 = (const float*)d_in[9];
  const float* bd2 = (const float*)d_in[10];
  const float* Wa  = (const float*)d_in[11];
  const float* ba  = (const float*)d_in[12];
  const float* g1  = (const float*)d_in[13];
  const float* b1  = (const float*)d_in[14];
  const float* g2  = (const float*)d_in[15];
  const float* b2  = (const float*)d_in[16];
  const float* Wf1 = (const float*)d_in[17];
  const float* bf1 = (const float*)d_in[18];
  const float* Wf2 = (const float*)d_in[19];
  const float* bf2 = (const float*)d_in[20];
  float* out = (float*)d_out;

  // workspace (float offsets; SZ = BNT*CC = 2,097,152):
  //  [0,SZ/2)        h bf16 (residual 1)
  //  [SZ/2,SZ)       hnb bf16 -> hres bf16 overlay (attn out, ffn2 resid)
  //  [SZ,1.5SZ)      q bf16   }
  //  [1.5SZ,2SZ)     kb bf16  } -> g bf16 overlays [SZ,3SZ) for FFN
  //  [2SZ,2.5SZ)     vb bf16  }
  //  [3SZ,3.5SZ)     h2 bf16
  //  [3.5SZ,3.625SZ) idx int[BNT*16]
  //  [3.625SZ,..)    bf16 weights (~0.43 MB)
  const size_t SZ = (size_t)BNT * CC;
  float* wsf = (float*)d_ws;
  bf16_t* hb    = (bf16_t*)wsf;
  bf16_t* hnb   = (bf16_t*)(wsf + SZ / 2);
  bf16_t* hresb = hnb;
  bf16_t* qb    = (bf16_t*)(wsf + SZ);
  bf16_t* kb    = (bf16_t*)(wsf + SZ + SZ / 2);
  bf16_t* vb    = (bf16_t*)(wsf + 2 * SZ);
  bf16_t* g     = (bf16_t*)(wsf + SZ);
  bf16_t* h2    = (bf16_t*)(wsf + 3 * SZ);
  int*    idxw  = (int*)(wsf + 3 * SZ + SZ / 2);
  bf16_t* Wqb   = (bf16_t*)(idxw + (size_t)BNT * KNB);
  bf16_t* Wkb   = Wqb  + 16384;
  bf16_t* Wvb   = Wkb  + 16384;
  bf16_t* Wd2b  = Wvb  + 16384;
  bf16_t* Wab   = Wd2b + 16384;
  bf16_t* Wf1b  = Wab  + 16384;
  bf16_t* Wf2b  = Wf1b + 65536;

  inproj_compw_k<<<256 + 56, 256, 0, stream>>>(x, Win, bin, g1, b1, hb, hnb,
                                               Wq, Wk, Wv, Wd2, Wa, Wf1, Wf2,
                                               Wqb, Wkb, Wvb, Wd2b, Wab, Wf1b, Wf2b);
  knn_qkv_k<<<4096 + 512, 256, 0, stream>>>(p, idxw, hnb, Wqb, Wkb, Wvb, qb, kb, vb);
  attn_k<<<BNT / 4, 256, 0, stream>>>(qb, kb, vb, p, idxw, Wd1, bd1, Wd2b, bd2, Wab, ba,
                                      g2, b2, hb, hresb, h2);
  ffn1_k<<<dim3(256, 2), 256, 0, stream>>>(h2, Wf1b, bf1, g);
  ffn2_k<<<256, 256, 0, stream>>>(g, Wf2b, bf2, hresb, out);
}

// Round 15
// 257.312 us; speedup vs baseline: 1.0450x; 1.0450x over previous
//
#include <hip/hip_runtime.h>

typedef __bf16 bf16_t;
typedef __bf16 bf16x8 __attribute__((ext_vector_type(8)));
typedef __bf16 bf16x2 __attribute__((ext_vector_type(2)));
typedef float  f32x4  __attribute__((ext_vector_type(4)));

#define MFMA16(a,b,c) __builtin_amdgcn_mfma_f32_16x16x32_bf16((a),(b),(c),0,0,0)

// ---- constants (problem is fixed-shape) ----
#define BB 8
#define NN 2048
#define CC 128
#define CIN 64
#define KNB 16            // neighbors
#define BNT (BB*NN)       // 16384 points

// XCD affinity: batch a block touches == blockIdx%8 == its XCD (R6-verified).
static __device__ __forceinline__ int remap256(int x) { return ((x & 7) << 5) | (x >> 3); }

static __device__ __forceinline__ bf16x8 cvt8(const float* src) {
  f32x4 a0 = *(const f32x4*)src;
  f32x4 a1 = *(const f32x4*)(src + 4);
  bf16x8 fr;
  fr[0] = (__bf16)a0[0]; fr[1] = (__bf16)a0[1]; fr[2] = (__bf16)a0[2]; fr[3] = (__bf16)a0[3];
  fr[4] = (__bf16)a1[0]; fr[5] = (__bf16)a1[1]; fr[6] = (__bf16)a1[2]; fr[7] = (__bf16)a1[3];
  return fr;
}

// ============================================================
// Kernel 1: in_proj + LN1 (R6-proven body; h stored bf16) with the
// weight-conversion blocks FUSED in (blocks 256..311, no LDS use).
// ============================================================
__global__ __launch_bounds__(256) void inproj_compw_k(
    const float* __restrict__ x, const float* __restrict__ Win, const float* __restrict__ bin,
    const float* __restrict__ g1, const float* __restrict__ b1,
    bf16_t* __restrict__ hb, bf16_t* __restrict__ hnb,
    const float* __restrict__ Wq, const float* __restrict__ Wk, const float* __restrict__ Wv,
    const float* __restrict__ Wd2, const float* __restrict__ Wa,
    const float* __restrict__ Wf1, const float* __restrict__ Wf2,
    bf16_t* __restrict__ Wqb, bf16_t* __restrict__ Wkb, bf16_t* __restrict__ Wvb,
    bf16_t* __restrict__ Wd2b, bf16_t* __restrict__ Wab,
    bf16_t* __restrict__ Wf1b, bf16_t* __restrict__ Wf2b) {
  __shared__ bf16_t As[64 * 72];
  __shared__ bf16_t Bs[128 * 72];
  __shared__ float hs[64 * 132];
  int t = threadIdx.x;
  if (blockIdx.x >= 256) {   // weight-conversion blocks (plain bf16 casts, RNE)
    int bi = blockIdx.x - 256;
    int mat = bi >> 3, xi = bi & 7;
    int nel = (mat >= 5) ? 65536 : 16384;
    const float* S = mat == 0 ? Wq : mat == 1 ? Wk : mat == 2 ? Wv : mat == 3 ? Wd2
                   : mat == 4 ? Wa : mat == 5 ? Wf1 : Wf2;
    bf16_t* D = mat == 0 ? Wqb : mat == 1 ? Wkb : mat == 2 ? Wvb : mat == 3 ? Wd2b
              : mat == 4 ? Wab : mat == 5 ? Wf1b : Wf2b;
    for (int i = xi * 256 + t; i * 8 < nel; i += 2048)
      *(bf16x8*)(D + i * 8) = cvt8(S + i * 8);
    return;
  }
  int lane = t & 63, w = t >> 6, quad = lane >> 4, l15 = lane & 15;
  int mBase = remap256(blockIdx.x) * 64;
  int b = mBase >> 11, n0 = mBase & (NN - 1);
  const float* xb = x + (size_t)b * CIN * NN;
  {
    int k = t >> 2, part = t & 3;
    #pragma unroll
    for (int i = 0; i < 4; ++i) {
      f32x4 v = *(const f32x4*)(xb + (size_t)k * NN + n0 + part * 16 + i * 4);
      #pragma unroll
      for (int j2 = 0; j2 < 4; ++j2) As[(part * 16 + i * 4 + j2) * 72 + k] = (__bf16)v[j2];
    }
  }
  {
    int row = t >> 1, seg = (t & 1) * 32;
    #pragma unroll
    for (int i = 0; i < 4; ++i)
      *(bf16x8*)(&Bs[row * 72 + seg + i * 8]) = cvt8(Win + (size_t)row * CIN + seg + i * 8);
  }
  __syncthreads();
  f32x4 acc[2][4] = {};
  #pragma unroll
  for (int s = 0; s < 2; ++s) {
    bf16x8 af[4];
    #pragma unroll
    for (int mt = 0; mt < 4; ++mt)
      af[mt] = *(const bf16x8*)(&As[(mt * 16 + l15) * 72 + s * 32 + quad * 8]);
    #pragma unroll
    for (int t2 = 0; t2 < 2; ++t2) {
      bf16x8 bfr = *(const bf16x8*)(&Bs[((w * 2 + t2) * 16 + l15) * 72 + s * 32 + quad * 8]);
      #pragma unroll
      for (int mt = 0; mt < 4; ++mt) acc[t2][mt] = MFMA16(af[mt], bfr, acc[t2][mt]);
    }
  }
  #pragma unroll
  for (int t2 = 0; t2 < 2; ++t2) {
    int col = (w * 2 + t2) * 16 + l15;
    float bv = bin[col];
    #pragma unroll
    for (int mt = 0; mt < 4; ++mt)
      #pragma unroll
      for (int reg = 0; reg < 4; ++reg)
        hs[(mt * 16 + quad * 4 + reg) * 132 + col] = acc[t2][mt][reg] + bv;
  }
  __syncthreads();
  {
    int row = t >> 2, c0 = (t & 3) * 32;
    float v[32];
    #pragma unroll
    for (int i = 0; i < 8; ++i) *(f32x4*)(v + i * 4) = *(const f32x4*)(&hs[row * 132 + c0 + i * 4]);
    float s1 = 0.f, s2 = 0.f;
    #pragma unroll
    for (int i = 0; i < 32; ++i) { s1 += v[i]; s2 += v[i] * v[i]; }
    s1 += __shfl_xor(s1, 1); s1 += __shfl_xor(s1, 2);
    s2 += __shfl_xor(s2, 1); s2 += __shfl_xor(s2, 2);
    float mu = s1 * (1.f / CC);
    float var = s2 * (1.f / CC) - mu * mu;
    float rs = rsqrtf(var + 1e-5f);
    bf16_t* hrow = hb + (size_t)(mBase + row) * CC + c0;
    #pragma unroll
    for (int i = 0; i < 4; ++i) {
      bf16x8 ho;
      #pragma unroll
      for (int j = 0; j < 8; ++j) ho[j] = (__bf16)v[i * 8 + j];
      *(bf16x8*)(hrow + i * 8) = ho;
    }
    bf16_t* hnrow = hnb + (size_t)(mBase + row) * CC + c0;
    #pragma unroll
    for (int i = 0; i < 4; ++i) {
      f32x4 g4a = ((const f32x4*)g1)[(c0 >> 2) + i * 2],     g4b = ((const f32x4*)g1)[(c0 >> 2) + i * 2 + 1];
      f32x4 b4a = ((const f32x4*)b1)[(c0 >> 2) + i * 2],     b4b = ((const f32x4*)b1)[(c0 >> 2) + i * 2 + 1];
      bf16x8 o;
      #pragma unroll
      for (int j = 0; j < 4; ++j) o[j]     = (__bf16)((v[i * 8 + j]     - mu) * rs * g4a[j] + b4a[j]);
      #pragma unroll
      for (int j = 0; j < 4; ++j) o[4 + j] = (__bf16)((v[i * 8 + 4 + j] - mu) * rs * g4b[j] + b4b[j]);
      *(bf16x8*)(hnrow + i * 8) = o;
    }
  }
}

// ============================================================
// KNN body (R6 verbatim, LDS passed in).
// ============================================================
static __device__ __forceinline__ void cas(double& a, double& b) {
  double lo = fmin(a, b), hi = fmax(a, b); a = lo; b = hi;
}
#define S8(K,o) \
  cas(K[o+0],K[o+1]); cas(K[o+2],K[o+3]); cas(K[o+4],K[o+5]); cas(K[o+6],K[o+7]); \
  cas(K[o+0],K[o+2]); cas(K[o+1],K[o+3]); cas(K[o+4],K[o+6]); cas(K[o+5],K[o+7]); \
  cas(K[o+1],K[o+2]); cas(K[o+5],K[o+6]); \
  cas(K[o+0],K[o+4]); cas(K[o+1],K[o+5]); cas(K[o+2],K[o+6]); cas(K[o+3],K[o+7]); \
  cas(K[o+2],K[o+4]); cas(K[o+3],K[o+5]); \
  cas(K[o+1],K[o+2]); cas(K[o+3],K[o+4]); cas(K[o+5],K[o+6]);
#define M8(K,a,b) \
  K[a+0]=fmin(K[a+0],K[b+7]); K[a+1]=fmin(K[a+1],K[b+6]); K[a+2]=fmin(K[a+2],K[b+5]); K[a+3]=fmin(K[a+3],K[b+4]); \
  K[a+4]=fmin(K[a+4],K[b+3]); K[a+5]=fmin(K[a+5],K[b+2]); K[a+6]=fmin(K[a+6],K[b+1]); K[a+7]=fmin(K[a+7],K[b+0]); \
  cas(K[a+0],K[a+4]); cas(K[a+1],K[a+5]); cas(K[a+2],K[a+6]); cas(K[a+3],K[a+7]); \
  cas(K[a+0],K[a+2]); cas(K[a+1],K[a+3]); cas(K[a+4],K[a+6]); cas(K[a+5],K[a+7]); \
  cas(K[a+0],K[a+1]); cas(K[a+2],K[a+3]); cas(K[a+4],K[a+5]); cas(K[a+6],K[a+7]);

static __device__ void knn_impl(float* sp, const float* __restrict__ p,
                                int* __restrict__ idxo, int bid) {
  float* px = sp; float* py = sp + NN; float* pz = sp + 2 * NN;
  int t = threadIdx.x;
  int b = bid >> 9;
  int g = bid & 511;
  const float* pb = p + (size_t)b * 3 * NN;
  for (int i = t; i < NN; i += 256) { px[i] = pb[i]; py[i] = pb[NN + i]; pz[i] = pb[2 * NN + i]; }
  __syncthreads();
  int w = t >> 6, lane = t & 63;
  int n = g * 4 + w;
  float pnx = px[n], pny = py[n], pnz = pz[n];
  double key[32];
  #pragma unroll
  for (int s = 0; s < 32; ++s) {
    int m = s * 64 + lane;
    float dx = pnx - px[m], dy = pny - py[m], dz = pnz - pz[m];
    float dist = dx * dx + dy * dy + dz * dz;
    unsigned db = (m == n) ? 0x7F800000u : __float_as_uint(dist);
    key[s] = __hiloint2double((int)db, m);
  }
  S8(key, 0); S8(key, 8); S8(key, 16); S8(key, 24);
  M8(key, 0, 8); M8(key, 16, 24); M8(key, 0, 16);
  const double DINF = __hiloint2double(0x7F900000, 0);
  int* myout = idxo + ((size_t)b * NN + n) * KNB;
  #pragma unroll 1
  for (int r = 0; r < 16; ++r) {
    double gm = key[0];
    #pragma unroll
    for (int off = 1; off < 64; off <<= 1) {
      double o = __shfl_xor(gm, off);
      gm = fmin(gm, o);
    }
    if (lane == 0) myout[r] = __double2loint(gm);
    bool win = (key[0] == gm);
    key[0] = win ? key[1] : key[0];
    key[1] = win ? key[2] : key[1];
    key[2] = win ? key[3] : key[2];
    key[3] = win ? key[4] : key[3];
    key[4] = win ? key[5] : key[4];
    key[5] = win ? key[6] : key[5];
    key[6] = win ? key[7] : key[6];
    key[7] = win ? DINF   : key[7];
  }
}

// ============================================================
// 64x64 GEMM body, BK=32, A & W bf16 (pre-converted).
// EPI: 1 relu->bf16, 2 +resid(bf16) transposed fp32 [B,C,N], 3 bf16.
// ============================================================
template<int EPI>
static __device__ void gemm_body(bf16_t* As, bf16_t* Bs,
    const bf16_t* __restrict__ Ab, const bf16_t* __restrict__ Wb, const float* __restrict__ bias,
    float* __restrict__ outF, bf16_t* __restrict__ outB, const bf16_t* __restrict__ resid,
    int mBase, int nBase, int Ncol, int Kdim) {
  int t = threadIdx.x;
  int lane = t & 63, w = t >> 6, quad = lane >> 4, l15 = lane & 15;
  int r = t >> 2, seg = (t & 3) * 8;
  f32x4 acc[4] = {{0,0,0,0},{0,0,0,0},{0,0,0,0},{0,0,0,0}};
  for (int k0 = 0; k0 < Kdim; k0 += 32) {
    __syncthreads();
    *(bf16x8*)(&As[r * 40 + seg]) = *(const bf16x8*)(Ab + (size_t)(mBase + r) * Kdim + k0 + seg);
    *(bf16x8*)(&Bs[r * 40 + seg]) = *(const bf16x8*)(Wb + (size_t)(nBase + r) * Kdim + k0 + seg);
    __syncthreads();
    bf16x8 bfr = *(const bf16x8*)(&Bs[(w * 16 + l15) * 40 + quad * 8]);
    #pragma unroll
    for (int mt = 0; mt < 4; ++mt) {
      bf16x8 afr = *(const bf16x8*)(&As[(mt * 16 + l15) * 40 + quad * 8]);
      acc[mt] = MFMA16(afr, bfr, acc[mt]);
    }
  }
  int n = nBase + w * 16 + l15;
  float bv = bias ? bias[n] : 0.f;
  #pragma unroll
  for (int mt = 0; mt < 4; ++mt) {
    #pragma unroll
    for (int reg = 0; reg < 4; ++reg) {
      int m = mBase + mt * 16 + quad * 4 + reg;
      float val = acc[mt][reg] + bv;
      if (EPI == 1) {
        outB[(size_t)m * Ncol + n] = (__bf16)fmaxf(val, 0.f);
      } else if (EPI == 3) {
        outB[(size_t)m * Ncol + n] = (__bf16)val;
      } else {
        val += (float)resid[(size_t)m * CC + n];
        int bo = m >> 11, np = m & (NN - 1);
        outF[((size_t)bo * CC + n) * NN + np] = val;
      }
    }
  }
}

template<int EPI>
__global__ __launch_bounds__(256) void gemm_k(
    const bf16_t* __restrict__ Ab, const bf16_t* __restrict__ Wb, const float* __restrict__ bias,
    float* __restrict__ outF, bf16_t* __restrict__ outB, const bf16_t* __restrict__ resid,
    int Ncol, int Kdim) {
  __shared__ bf16_t As[64 * 40];
  __shared__ bf16_t Bs[64 * 40];
  gemm_body<EPI>(As, Bs, Ab, Wb, bias, outF, outB, resid,
                 remap256(blockIdx.x) * 64, blockIdx.y * 64, Ncol, Kdim);
}

// ============================================================
// Fused knn + qkv dispatch (R11/R13-proven).
// ============================================================
__global__ __launch_bounds__(256) void knn_qkv_k(
    const float* __restrict__ p, int* __restrict__ idxo,
    const bf16_t* __restrict__ hnb,
    const bf16_t* __restrict__ Wqb, const bf16_t* __restrict__ Wkb, const bf16_t* __restrict__ Wvb,
    bf16_t* __restrict__ qb, bf16_t* __restrict__ kb, bf16_t* __restrict__ vb) {
  __shared__ __align__(16) char smem[3 * NN * 4];   // 24576 B
  if (blockIdx.x < 4096) {
    knn_impl((float*)smem, p, idxo, blockIdx.x);
  } else {
    bf16_t* As = (bf16_t*)smem;
    bf16_t* Bs = As + 64 * 40;
    int bx = blockIdx.x - 4096;
    int yy = bx >> 8, xx = bx & 255;
    int sel = yy >> 1;
    int mB = remap256(xx) * 64, nB = (yy & 1) * 64;
    if (sel == 0)      gemm_body<3>(As, Bs, hnb, Wqb, nullptr, nullptr, qb, nullptr, mB, nB, CC, CC);
    else if (sel == 1) gemm_body<3>(As, Bs, hnb, Wkb, nullptr, nullptr, kb, nullptr, mB, nB, CC, CC);
    else               gemm_body<3>(As, Bs, hnb, Wvb, nullptr, nullptr, vb, nullptr, mB, nB, CC, CC);
  }
}

// ============================================================
// Kernel 5: fused neighbor attention (R13 verbatim — 75 µs proven).
// ============================================================
__global__ __launch_bounds__(256, 3) void attn_k(
    const bf16_t* __restrict__ qbuf, const bf16_t* __restrict__ kbuf, const bf16_t* __restrict__ vbuf,
    const float* __restrict__ p, const int* __restrict__ idx,
    const float* __restrict__ Wd1, const float* __restrict__ bd1,
    const bf16_t* __restrict__ Wd2b, const float* __restrict__ bd2,
    const bf16_t* __restrict__ Wab, const float* __restrict__ ba,
    const float* __restrict__ g2, const float* __restrict__ b2,
    const bf16_t* __restrict__ hb, bf16_t* __restrict__ hresb, bf16_t* __restrict__ h2) {
  __shared__ bf16_t ts[64 * 136];      // u matrix only
  __shared__ float hrs[4 * 128];
  __shared__ f32x4 wd1s[128];          // {Wd1[c][0..2], bd1[c]}
  __shared__ f32x4 rels4[64];          // {rx,ry,rz,0}
  __shared__ int idxs[64];
  int t = threadIdx.x;
  int lane = t & 63, w = t >> 6, quad = lane >> 4, l15 = lane & 15;
  int batch = blockIdx.x & 7, grp = blockIdx.x >> 3;
  int bn0 = batch * NN + grp * 4;
  int b = batch;
  const float* pb = p + (size_t)b * 3 * NN;
  int col0 = w * 32 + l15;
  int col1 = col0 + 16;

  bf16x8 Bd[2][4];
  #pragma unroll
  for (int t2 = 0; t2 < 2; ++t2) {
    int row = w * 32 + t2 * 16 + l15;
    #pragma unroll
    for (int s = 0; s < 4; ++s)
      Bd[t2][s] = *(const bf16x8*)(Wd2b + (size_t)row * CC + s * 32 + quad * 8);
  }

  if (t < 64) {
    int jj = idx[(size_t)bn0 * KNB + t];
    idxs[t] = jj;
    int npt = grp * 4 + (t >> 4);
    f32x4 rv;
    rv[0] = pb[npt]          - pb[jj];
    rv[1] = pb[NN + npt]     - pb[NN + jj];
    rv[2] = pb[2 * NN + npt] - pb[2 * NN + jj];
    rv[3] = 0.f;
    rels4[t] = rv;
  }
  if (t < 128) {
    f32x4 wv;
    wv[0] = Wd1[t * 3]; wv[1] = Wd1[t * 3 + 1]; wv[2] = Wd1[t * 3 + 2]; wv[3] = bd1[t];
    wd1s[t] = wv;
  }
  __syncthreads();

  float qv[2][4];
  #pragma unroll
  for (int mt = 0; mt < 4; ++mt) {
    qv[0][mt] = (float)qbuf[(size_t)(bn0 + mt) * CC + col0];
    qv[1][mt] = (float)qbuf[(size_t)(bn0 + mt) * CC + col1];
  }
  float kreg[2][4][4];
  #pragma unroll
  for (int mt = 0; mt < 4; ++mt)
    #pragma unroll
    for (int reg = 0; reg < 4; ++reg) {
      size_t base = (size_t)(b * NN + idxs[mt * 16 + quad * 4 + reg]) * CC;
      kreg[0][mt][reg] = (float)kbuf[base + col0];
      kreg[1][mt][reg] = (float)kbuf[base + col1];
    }

  f32x4 relv[4];
  #pragma unroll
  for (int mt = 0; mt < 4; ++mt) relv[mt] = rels4[mt * 16 + l15];
  f32x4 accd[2][4] = {};
  #pragma unroll
  for (int s = 0; s < 4; ++s) {
    bf16x8 af[4];
    #pragma unroll
    for (int j = 0; j < 8; ++j) {
      f32x4 wv = wd1s[s * 32 + quad * 8 + j];
      #pragma unroll
      for (int mt = 0; mt < 4; ++mt) {
        float tv = fmaf(wv[0], relv[mt][0], fmaf(wv[1], relv[mt][1], fmaf(wv[2], relv[mt][2], wv[3])));
        af[mt][j] = (__bf16)fmaxf(tv, 0.f);
      }
    }
    #pragma unroll
    for (int t2 = 0; t2 < 2; ++t2)
      #pragma unroll
      for (int mt = 0; mt < 4; ++mt)
        accd[t2][mt] = MFMA16(af[mt], Bd[t2][s], accd[t2][mt]);
  }

  {
    float b2v0 = bd2[col0], b2v1 = bd2[col1];
    #pragma unroll
    for (int mt = 0; mt < 4; ++mt)
      #pragma unroll
      for (int reg = 0; reg < 4; ++reg) {
        int row = mt * 16 + quad * 4 + reg;
        float d0 = accd[0][mt][reg] + b2v0;
        float d1 = accd[1][mt][reg] + b2v1;
        accd[0][mt][reg] = d0;
        accd[1][mt][reg] = d1;
        ts[row * 136 + col0] = (__bf16)(qv[0][mt] - kreg[0][mt][reg] + d0);
        ts[row * 136 + col1] = (__bf16)(qv[1][mt] - kreg[1][mt][reg] + d1);
      }
  }
  __syncthreads();

  float vreg[2][4][4];
  #pragma unroll
  for (int mt = 0; mt < 4; ++mt)
    #pragma unroll
    for (int reg = 0; reg < 4; ++reg) {
      size_t base = (size_t)(b * NN + idxs[mt * 16 + quad * 4 + reg]) * CC;
      vreg[0][mt][reg] = (float)vbuf[base + col0];
      vreg[1][mt][reg] = (float)vbuf[base + col1];
    }
  float hv[2][4];
  if (quad == 0) {
    #pragma unroll
    for (int mt = 0; mt < 4; ++mt) {
      hv[0][mt] = (float)hb[(size_t)(bn0 + mt) * CC + col0];
      hv[1][mt] = (float)hb[(size_t)(bn0 + mt) * CC + col1];
    }
  }
  bf16x8 Ba[2][4];
  #pragma unroll
  for (int t2 = 0; t2 < 2; ++t2) {
    int row = w * 32 + t2 * 16 + l15;
    #pragma unroll
    for (int s = 0; s < 4; ++s)
      Ba[t2][s] = *(const bf16x8*)(Wab + (size_t)row * CC + s * 32 + quad * 8);
  }

  f32x4 accl[2][4] = {};
  #pragma unroll
  for (int s = 0; s < 4; ++s) {
    bf16x8 af[4];
    #pragma unroll
    for (int mt = 0; mt < 4; ++mt)
      af[mt] = *(const bf16x8*)(&ts[(mt * 16 + l15) * 136 + s * 32 + quad * 8]);
    #pragma unroll
    for (int t2 = 0; t2 < 2; ++t2)
      #pragma unroll
      for (int mt = 0; mt < 4; ++mt)
        accl[t2][mt] = MFMA16(af[mt], Ba[t2][s], accl[t2][mt]);
  }

  #pragma unroll
  for (int t2 = 0; t2 < 2; ++t2) {
    int col = t2 ? col1 : col0;
    float bav = ba[col];
    #pragma unroll
    for (int mt = 0; mt < 4; ++mt) {
      float lv0 = accl[t2][mt][0] + bav, lv1 = accl[t2][mt][1] + bav;
      float lv2 = accl[t2][mt][2] + bav, lv3 = accl[t2][mt][3] + bav;
      float mx = fmaxf(fmaxf(lv0, lv1), fmaxf(lv2, lv3));
      mx = fmaxf(mx, __shfl_xor(mx, 16));
      mx = fmaxf(mx, __shfl_xor(mx, 32));
      float e0 = __expf(lv0 - mx), e1 = __expf(lv1 - mx);
      float e2 = __expf(lv2 - mx), e3 = __expf(lv3 - mx);
      float ss = e0 + e1 + e2 + e3;
      ss += __shfl_xor(ss, 16); ss += __shfl_xor(ss, 32);
      float yv = e0 * (vreg[t2][mt][0] + accd[t2][mt][0])
               + e1 * (vreg[t2][mt][1] + accd[t2][mt][1])
               + e2 * (vreg[t2][mt][2] + accd[t2][mt][2])
               + e3 * (vreg[t2][mt][3] + accd[t2][mt][3]);
      yv += __shfl_xor(yv, 16); yv += __shfl_xor(yv, 32);
      if (quad == 0) {
        float hvv = hv[t2][mt] + yv / ss;
        hresb[(size_t)(bn0 + mt) * CC + col] = (__bf16)hvv;
        hrs[mt * 128 + col] = hvv;
      }
    }
  }
  __syncthreads();

  {
    int c0 = lane * 2;
    float v0 = hrs[w * 128 + c0], v1 = hrs[w * 128 + c0 + 1];
    float s1 = v0 + v1, s2 = v0 * v0 + v1 * v1;
    #pragma unroll
    for (int off = 1; off < 64; off <<= 1) { s1 += __shfl_xor(s1, off); s2 += __shfl_xor(s2, off); }
    float mu = s1 * (1.f / CC);
    float var = s2 * (1.f / CC) - mu * mu;
    float rs = rsqrtf(var + 1e-5f);
    bf16x2 o;
    o[0] = (__bf16)((v0 - mu) * rs * g2[c0] + b2[c0]);
    o[1] = (__bf16)((v1 - mu) * rs * g2[c0 + 1] + b2[c0 + 1]);
    *(bf16x2*)(h2 + (size_t)(bn0 + w) * CC + c0) = o;
  }
}

// ============================================================
extern "C" void kernel_launch(void* const* d_in, const int* in_sizes, int n_in,
                              void* d_out, int out_size, void* d_ws, size_t ws_size,
                              hipStream_t stream) {
  const float* x   = (const float*)d_in[0];
  const float* p   = (const float*)d_in[1];
  const float* Win = (const float*)d_in[2];
  const float* bin = (const float*)d_in[3];
  const float* Wq  = (const float*)d_in[4];
  const float* Wk  = (const float*)d_in[5];
  const float* Wv  = (const float*)d_in[6];
  const float* Wd1 = (const float*)d_in[7];
  const float* bd1 = (const float*)d_in[8];
  const float* Wd2 = (const float*)d_in[9];
  const float* bd2 = (const float*)d_in[10];
  const float* Wa  = (const float*)d_in[11];
  const float* ba  = (const float*)d_in[12];
  const float* g1  = (const float*)d_in[13];
  const float* b1  = (const float*)d_in[14];
  const float* g2  = (const float*)d_in[15];
  const float* b2  = (const float*)d_in[16];
  const float* Wf1 = (const float*)d_in[17];
  const float* bf1 = (const float*)d_in[18];
  const float* Wf2 = (const float*)d_in[19];
  const float* bf2 = (const float*)d_in[20];
  float* out = (float*)d_out;

  // workspace (float offsets; SZ = BNT*CC = 2,097,152):
  //  [0,SZ/2)        h bf16 (residual 1)
  //  [SZ/2,SZ)       hnb bf16 -> hres bf16 overlay (attn out, ffn2 resid)
  //  [SZ,1.5SZ)      q bf16   }
  //  [1.5SZ,2SZ)     kb bf16  } -> g bf16 overlays [SZ,3SZ) for FFN
  //  [2SZ,2.5SZ)     vb bf16  }
  //  [3SZ,3.5SZ)     h2 bf16
  //  [3.5SZ,3.625SZ) idx int[BNT*16]
  //  [3.625SZ,..)    bf16 weights (~0.43 MB)
  const size_t SZ = (size_t)BNT * CC;
  float* wsf = (float*)d_ws;
  bf16_t* hb    = (bf16_t*)wsf;
  bf16_t* hnb   = (bf16_t*)(wsf + SZ / 2);
  bf16_t* hresb = hnb;
  bf16_t* qb    = (bf16_t*)(wsf + SZ);
  bf16_t* kb    = (bf16_t*)(wsf + SZ + SZ / 2);
  bf16_t* vb    = (bf16_t*)(wsf + 2 * SZ);
  bf16_t* g     = (bf16_t*)(wsf + SZ);
  bf16_t* h2    = (bf16_t*)(wsf + 3 * SZ);
  int*    idxw  = (int*)(wsf + 3 * SZ + SZ / 2);
  bf16_t* Wqb   = (bf16_t*)(idxw + (size_t)BNT * KNB);
  bf16_t* Wkb   = Wqb  + 16384;
  bf16_t* Wvb   = Wkb  + 16384;
  bf16_t* Wd2b  = Wvb  + 16384;
  bf16_t* Wab   = Wd2b + 16384;
  bf16_t* Wf1b  = Wab  + 16384;
  bf16_t* Wf2b  = Wf1b + 65536;

  inproj_compw_k<<<256 + 56, 256, 0, stream>>>(x, Win, bin, g1, b1, hb, hnb,
                                               Wq, Wk, Wv, Wd2, Wa, Wf1, Wf2,
                                               Wqb, Wkb, Wvb, Wd2b, Wab, Wf1b, Wf2b);
  knn_qkv_k<<<4096 + 1536, 256, 0, stream>>>(p, idxw, hnb, Wqb, Wkb, Wvb, qb, kb, vb);
  attn_k<<<BNT / 4, 256, 0, stream>>>(qb, kb, vb, p, idxw, Wd1, bd1, Wd2b, bd2, Wab, ba,
                                      g2, b2, hb, hresb, h2);
  gemm_k<1><<<dim3(BNT / 64, 8), 256, 0, stream>>>(h2, Wf1b, bf1, nullptr, g, nullptr, 4 * CC, CC);
  gemm_k<2><<<dim3(BNT / 64, 2), 256, 0, stream>>>(g, Wf2b, bf2, out, nullptr, hresb, CC, 4 * CC);
}